// Round 5
// baseline (144.538 us; speedup 1.0000x reference)
//
#include <hip/hip_runtime.h>
#include <hip/hip_bf16.h>

typedef _Float16 f16;
typedef _Float16 f16x8 __attribute__((ext_vector_type(8)));
typedef float f32x4 __attribute__((ext_vector_type(4)));

#define NN 200000
#define KK 512
#define CC 64
#define JJ 32
// W_frag: 48 F-ksteps (16 w1 | 16 wh | 16 wl) x 4 coltiles x 64 lanes x 8 f16
#define WFRAG_ELEMS (48 * 4 * 64 * 8) /* 98304 f16 = 192 KiB */

__device__ inline void gload_lds16(const void* g, void* l) {
  __builtin_amdgcn_global_load_lds(
      (const __attribute__((address_space(1))) void*)g,
      (__attribute__((address_space(3))) void*)l, 16, 0, 0);
}

__device__ inline f32x4 ntl(const float* p) {
  return __builtin_nontemporal_load(reinterpret_cast<const f32x4*>(p));
}

// Pack W into MFMA-B fragment order: elem idx = ((kF*4 + ct)*64 + lane)*8 + i
// holds W[Fk = (kF&15)*32 + (lane>>4)*8 + i][c = ct*16 + (lane&15)], section kF>>4:
//   0: w1 = -0.5*(exp(-lv)-1)   (vs xx, centered variance term)
//   1: wh = f16(mu*exp(-lv))    (vs xh and xl)
//   2: wl = residual of wh      (vs xh)
__global__ __launch_bounds__(256) void fill_w(const float* __restrict__ mu,
                                              const float* __restrict__ lv,
                                              f16* __restrict__ wfrag) {
  int idx = blockIdx.x * 256 + threadIdx.x;
  int i = idx & 7, l = (idx >> 3) & 63, ct = (idx >> 9) & 3, kF = idx >> 11;
  int k = (kF & 15) * 32 + (l >> 4) * 8 + i;
  int c = ct * 16 + (l & 15);
  int sec = kF >> 4;
  float lvv = lv[c * KK + k];
  float w;
  if (sec == 0) {
    w = -0.5f * expm1f(-lvv);
  } else {
    float w2 = mu[c * KK + k] * expf(-lvv);
    float wh = (float)(f16)w2;
    w = (sec == 1) ? wh : (w2 - wh);
  }
  wfrag[idx] = (f16)w;
}

// bias[j][c] = log(alpha*beta[c] + njk[j][c]) - 0.5*(sum_k(mu^2*iv + lv) + K*ln(2pi))
__global__ __launch_bounds__(64) void fill_bias(const float* __restrict__ mu,
                                                const float* __restrict__ lv,
                                                const float* __restrict__ beta,
                                                const float* __restrict__ njk,
                                                const float* __restrict__ alphap,
                                                float* __restrict__ bias) {
  int c = blockIdx.x;
  int lane = threadIdx.x;
  float s = 0.0f;
  for (int k = lane; k < KK; k += 64) {
    float l2 = lv[c * KK + k];
    float m = mu[c * KK + k];
    s += fmaf(m * m, expf(-l2), l2);
  }
  #pragma unroll
  for (int d = 1; d < 64; d <<= 1) s += __shfl_xor(s, d, 64);
  float base = -0.5f * (s + 512.0f * 1.8378770664093453f);
  if (lane < JJ)
    bias[lane * CC + c] = logf(alphap[0] * beta[c] + njk[lane * CC + c]) + base;
}

// 4-wave wg, 128 rows/wg (32/wave). LDS double-buffered W staging (as R3,
// plain __syncthreads — R4's pinned vmcnt regressed). NEW: x loaded in
// 2-step groups (256 B contiguous per row issued back-to-back) to halve
// HBM page activations per row (16 -> 8).
// Layouts (m89-verified): A row=l&15, k=(l>>4)*8+i; D col=l&15, row=(l>>4)*4+reg.
__global__ __launch_bounds__(256, 3) void gmm_main(
    const float* __restrict__ x, const int* __restrict__ ms,
    const f16* __restrict__ wfrag, const float* __restrict__ bias,
    float* __restrict__ out) {
  __shared__ char lds[2 * 12288];
  const int t = threadIdx.x;
  const int lane = t & 63;
  const int wv = t >> 6;
  const int lr = lane & 15;   // A row / D col / B col within tile
  const int kg = lane >> 4;   // k-group (8 consecutive k each)
  const long row0 = (long)blockIdx.x * 128 + wv * 32;
  const bool valid = row0 < NN;            // last wg: invalid waves stay for barriers
  const long r0 = valid ? row0 + lr : 0;
  const long r1 = valid ? row0 + 16 + lr : 0;

  const float* xp0 = x + r0 * KK + kg * 8;
  const float* xp1 = x + r1 * KK + kg * 8;
  const char* wfb = (const char*)wfrag;
  const int lsec = wv * 1024 + lane * 16;  // 16B slot within a 4 KiB sec-chunk

  f32x4 acc[2][4];
  #pragma unroll
  for (int rt = 0; rt < 2; ++rt)
    #pragma unroll
    for (int ct = 0; ct < 4; ++ct) acc[rt][ct] = (f32x4)0.0f;

  // x group buffers: [0,1]=rt0 even-step, [2,3]=rt1 even-step,
  //                  [4,5]=rt0 odd-step,  [6,7]=rt1 odd-step
  f32x4 XA[8], XB[8];

  // load group covering steps s,s+1 — per row 256 B issued back-to-back
  auto load_group = [&](f32x4 (&G)[8], int s) {
    const float* p0 = xp0 + s * 32;
    const float* p1 = xp1 + s * 32;
    G[0] = ntl(p0);      G[1] = ntl(p0 + 4);
    G[4] = ntl(p0 + 32); G[5] = ntl(p0 + 36);
    G[2] = ntl(p1);      G[3] = ntl(p1 + 4);
    G[6] = ntl(p1 + 32); G[7] = ntl(p1 + 36);
  };

  // prologue: stage chunk0 -> buf0; groups 0 (steps 0,1) and 1 (steps 2,3)
  #pragma unroll
  for (int sec = 0; sec < 3; ++sec)
    gload_lds16(wfb + sec * 65536 + lsec, lds + sec * 4096 + wv * 1024);
  load_group(XA, 0);
  load_group(XB, 2);
  __syncthreads();

  // convert one step's x (p = step parity within group) to f16 frags
  auto convert = [&](const f32x4 (&G)[8], int p, f16x8 (&fxx)[2],
                     f16x8 (&fxh)[2], f16x8 (&fxl)[2]) {
    #pragma unroll
    for (int rt = 0; rt < 2; ++rt) {
      const f32x4& a = G[p * 4 + rt * 2];
      const f32x4& b = G[p * 4 + rt * 2 + 1];
      #pragma unroll
      for (int i = 0; i < 8; ++i) {
        float v = (i < 4) ? a[i] : b[i - 4];
        f16 h = (f16)v;
        fxh[rt][i] = h;
        fxl[rt][i] = (f16)(v - (float)h);
        fxx[rt][i] = (f16)(v * v);
      }
    }
  };

  auto mfma_step = [&](int s, const f16x8 (&fxx)[2], const f16x8 (&fxh)[2],
                       const f16x8 (&fxl)[2]) {
    const f16* lbase = (const f16*)(lds + (s & 1) * 12288) + lane * 8;
    #pragma unroll
    for (int ct = 0; ct < 4; ++ct) {
      f16x8 bw1 = *reinterpret_cast<const f16x8*>(lbase + ct * 512);
      f16x8 bwh = *reinterpret_cast<const f16x8*>(lbase + 2048 + ct * 512);
      f16x8 bwl = *reinterpret_cast<const f16x8*>(lbase + 4096 + ct * 512);
      #pragma unroll
      for (int rt = 0; rt < 2; ++rt) {
        acc[rt][ct] = __builtin_amdgcn_mfma_f32_16x16x32_f16(fxx[rt], bw1, acc[rt][ct], 0, 0, 0);
        acc[rt][ct] = __builtin_amdgcn_mfma_f32_16x16x32_f16(fxh[rt], bwh, acc[rt][ct], 0, 0, 0);
        acc[rt][ct] = __builtin_amdgcn_mfma_f32_16x16x32_f16(fxh[rt], bwl, acc[rt][ct], 0, 0, 0);
        acc[rt][ct] = __builtin_amdgcn_mfma_f32_16x16x32_f16(fxl[rt], bwh, acc[rt][ct], 0, 0, 0);
      }
    }
  };

  auto stage_chunk = [&](int s) {  // stage W chunk s+1 into buf (s+1)&1
    if (s < 15) {
      const char* gsrc = wfb + (s + 1) * 4096;
      char* ldst = lds + ((s + 1) & 1) * 12288;
      #pragma unroll
      for (int sec = 0; sec < 3; ++sec)
        gload_lds16(gsrc + sec * 65536 + lsec, ldst + sec * 4096 + wv * 1024);
    }
  };

  // consumes CUR (steps s,s+1), loads steps s+2,s+3 into NXT
  auto step_pair = [&](int s, const f32x4 (&CUR)[8], f32x4 (&NXT)[8]) {
    f16x8 fxx[2], fxh[2], fxl[2];
    // even step
    stage_chunk(s);
    convert(CUR, 0, fxx, fxh, fxl);
    load_group(NXT, (s + 2 <= 14) ? s + 2 : 14);  // tail: dead reload, in-bounds
    mfma_step(s, fxx, fxh, fxl);
    __syncthreads();
    // odd step
    stage_chunk(s + 1);
    convert(CUR, 1, fxx, fxh, fxl);
    mfma_step(s + 1, fxx, fxh, fxl);
    __syncthreads();
  };

  #pragma unroll 1
  for (int tt = 0; tt < 4; ++tt) {
    step_pair(tt * 4, XA, XB);
    step_pair(tt * 4 + 2, XB, XA);
  }

  // Epilogue: bias add + softmax across 64 cols (4 regs x 16 lanes) + store.
  if (valid) {
    #pragma unroll
    for (int rt = 0; rt < 2; ++rt) {
      long rbase = row0 + rt * 16 + kg * 4;
      #pragma unroll
      for (int r = 0; r < 4; ++r) {
        int j = ms[rbase + r];
        const float* bj = bias + j * CC + lr;
        float v0 = acc[rt][0][r] + bj[0];
        float v1 = acc[rt][1][r] + bj[16];
        float v2 = acc[rt][2][r] + bj[32];
        float v3 = acc[rt][3][r] + bj[48];
        float m = fmaxf(fmaxf(v0, v1), fmaxf(v2, v3));
        #pragma unroll
        for (int d = 1; d < 16; d <<= 1) m = fmaxf(m, __shfl_xor(m, d, 64));
        float e0 = __expf(v0 - m), e1 = __expf(v1 - m);
        float e2 = __expf(v2 - m), e3 = __expf(v3 - m);
        float sum = (e0 + e1) + (e2 + e3);
        #pragma unroll
        for (int d = 1; d < 16; d <<= 1) sum += __shfl_xor(sum, d, 64);
        float inv = 1.0f / sum;
        float* o = out + (size_t)rbase * CC + r * CC + lr;
        __builtin_nontemporal_store(e0 * inv, o);
        __builtin_nontemporal_store(e1 * inv, o + 16);
        __builtin_nontemporal_store(e2 * inv, o + 32);
        __builtin_nontemporal_store(e3 * inv, o + 48);
      }
    }
  }
}

extern "C" void kernel_launch(void* const* d_in, const int* in_sizes, int n_in,
                              void* d_out, int out_size, void* d_ws, size_t ws_size,
                              hipStream_t stream) {
  const float* x     = (const float*)d_in[0];
  const float* mu    = (const float*)d_in[1];
  const float* lv    = (const float*)d_in[2];
  const float* beta  = (const float*)d_in[3];
  const float* njk   = (const float*)d_in[4];
  const float* alpha = (const float*)d_in[5];
  const int*   ms    = (const int*)d_in[6];
  float* out = (float*)d_out;

  f16* wfrag  = (f16*)d_ws;
  float* bias = (float*)((char*)d_ws + WFRAG_ELEMS * sizeof(f16));

  fill_w<<<WFRAG_ELEMS / 256, 256, 0, stream>>>(mu, lv, wfrag);
  fill_bias<<<CC, 64, 0, stream>>>(mu, lv, beta, njk, alpha, bias);
  gmm_main<<<(NN + 127) / 128, 256, 0, stream>>>(x, ms, wfrag, bias, out);
}